// Round 14
// baseline (139.824 us; speedup 1.0000x reference)
//
#include <hip/hip_runtime.h>
#include <hip/hip_bf16.h>
#include <stdint.h>
#include <stddef.h>

// Problem constants (from reference)
#define IN_F     1024
#define OUT_F    1024
#define BATCH    4096
#define NSPLINE  8            // GRID_SIZE + SPLINE_ORDER
#define KDIM     (IN_F * 9)   // 9216 : plane 0 = silu(x), planes 1..8 = spline basis
#define GRIDPTS  12           // GRID_SIZE + 2*SPLINE_ORDER + 1

typedef __bf16 bf16;
typedef __bf16 bf16x8 __attribute__((ext_vector_type(8)));
typedef float  f32x4  __attribute__((ext_vector_type(4)));

// -------------------------------------------------------------------------
// Kernel 1 (fused prep): blocks [0,16384) build augmented activation
// A[BATCH][KDIM] bf16; blocks [16384,20480) pack W[OUT_F][KDIM] bf16.
// -------------------------------------------------------------------------
#define NB_BUILD (BATCH * IN_F / 256)   // 16384
#define NB_PACK  (OUT_F * IN_F / 256)   // 4096

__global__ __launch_bounds__(256) void prep(const float* __restrict__ x,
                                            const float* __restrict__ grid,
                                            const float* __restrict__ bw,
                                            const float* __restrict__ sw,
                                            const float* __restrict__ sc,
                                            bf16* __restrict__ A,
                                            bf16* __restrict__ W)
{
    __shared__ float g[GRIDPTS];
    __shared__ float rec[33];   // rec[(k-1)*11 + j] = 1/(g[j+k]-g[j]+1e-8)

    if (blockIdx.x < NB_BUILD) {
        // ---------------- build_A ----------------
        if (threadIdx.x < GRIDPTS) g[threadIdx.x] = grid[threadIdx.x];  // row 0
        __syncthreads();
        if (threadIdx.x < 33) {
            const int k = threadIdx.x / 11 + 1;
            const int j = threadIdx.x % 11;
            if (j + k <= 11) rec[threadIdx.x] = 1.0f / (g[j + k] - g[j] + 1e-8f);
        }
        __syncthreads();

        const int idx = blockIdx.x * 256 + threadIdx.x;   // b*IN_F + i
        const int b = idx >> 10;
        const int i = idx & 1023;
        const float xv = x[idx];

        float bs[11];
#pragma unroll
        for (int j = 0; j < 11; ++j)
            bs[j] = (xv >= g[j] && xv < g[j + 1]) ? 1.0f : 0.0f;

#pragma unroll
        for (int k = 1; k <= 3; ++k) {
            const float* rk = &rec[(k - 1) * 11];
#pragma unroll
            for (int j = 0; j < 10; ++j) {
                if (j <= 10 - k) {
                    bs[j] = (xv - g[j]) * rk[j] * bs[j]
                          + (g[j + k + 1] - xv) * rk[j + 1] * bs[j + 1];
                }
            }
        }

        const float si = xv / (1.0f + __expf(-xv));   // silu

        bf16* rowp = A + (size_t)b * KDIM;
        rowp[i] = (bf16)si;
#pragma unroll
        for (int j = 0; j < NSPLINE; ++j)
            rowp[(size_t)(j + 1) * IN_F + i] = (bf16)bs[j];
    } else {
        // ---------------- pack_W ----------------
        const int idx = (blockIdx.x - NB_BUILD) * 256 + threadIdx.x;   // o*IN_F + i
        const int i = idx & 1023;
        const float s = sc[idx];

        bf16* rowp = W + (size_t)(idx >> 10) * KDIM;
        rowp[i] = (bf16)bw[idx];

        const float4* swv = (const float4*)(sw + (size_t)idx * NSPLINE);
        const float4 w0 = swv[0];
        const float4 w1 = swv[1];
        rowp[(size_t)1 * IN_F + i] = (bf16)(w0.x * s);
        rowp[(size_t)2 * IN_F + i] = (bf16)(w0.y * s);
        rowp[(size_t)3 * IN_F + i] = (bf16)(w0.z * s);
        rowp[(size_t)4 * IN_F + i] = (bf16)(w0.w * s);
        rowp[(size_t)5 * IN_F + i] = (bf16)(w1.x * s);
        rowp[(size_t)6 * IN_F + i] = (bf16)(w1.y * s);
        rowp[(size_t)7 * IN_F + i] = (bf16)(w1.z * s);
        rowp[(size_t)8 * IN_F + i] = (bf16)(w1.w * s);
    }
}

// -------------------------------------------------------------------------
// Kernel 2: 256x256x64 pipelined 4-phase split-K GEMM (T1+T2+T4+T5),
// r12 schedule with K-loop address VALU eliminated (HK technique 8):
//  - LDS split: A halves in slots 0-3 (first 64 KB), B halves in slots 4-7.
//  - 2-tile unroll (NT even) -> all slot indices are LITERALS; every
//    ds_read_b128 uses one of 12 precomputed per-lane offsets.
//  - Staging via 4 advancing global pointers + literal byte offsets.
// FIX vs r13: prologue halves 0,1,2 live at byte offsets 0,64,128 from the
// tile-0 pointer (one half = 32 bf16 = 64 B); r13 wrongly used 0,128,256.
// Ring/vmcnt (per-operand rings of 4): tile t stages {A,B}(2t+3) in P1/P2,
// {A,B}(2t+4) in P3/P4; end-of-tile vmcnt(4) leaves exactly the (2t+4)
// pair outstanding => halves <= 2t+3 landed for ALL waves before the
// barrier; tile t+1 reads halves 2t+2, 2t+3 only.
// -------------------------------------------------------------------------
#define BM8 256
#define BN8 256
#define BK8 64
#define SPLIT 4
#define KLEN (KDIM / SPLIT)   // 2304
#define NT8  (KLEN / BK8)     // 36 (even)

#define GLOAD_LDS16(gp, lp)                                                          \
    __builtin_amdgcn_global_load_lds((const __attribute__((address_space(1))) void*)(gp), \
                                     (__attribute__((address_space(3))) void*)(lp), 16, 0, 0)

__global__ __launch_bounds__(512, 2) void gemm8(const bf16* __restrict__ A,
                                                const bf16* __restrict__ B,
                                                float* __restrict__ C)
{
    __shared__ bf16 lds[8 * 8192];   // A: 4x16KB slots, B: 4x16KB slots

    const int tid  = threadIdx.x;
    const int wave = tid >> 6;
    const int lane = tid & 63;

    // bijective XCD swizzle (gridDim.x % 8 == 0)
    const int nwg  = gridDim.x;
    const int q    = nwg >> 3;
    const int wgid = (blockIdx.x & 7) * q + (blockIdx.x >> 3);
    const int nxy  = (BATCH / BM8) * (OUT_F / BN8);   // 64
    const int z    = wgid / nxy;
    const int rem  = wgid - z * nxy;
    const int by   = rem >> 4;           // 0..3
    const int bx   = rem & 15;           // 0..15

    const int bm   = bx * BM8;
    const int bcol = by * BN8;
    const int kBase = z * KLEN;
    C += (size_t)z * BATCH * OUT_F;      // partial buffer for this K-slice

    const int wr = (wave >> 2) * 128;    // 2 M-waves
    const int wc = (wave & 3) * 64;      // 4 N-waves

    f32x4 acc[8][4] = {};

    // staging: thread covers row tid/4; global k-chunk pre-swizzled (T2/rule21)
    const int srow = tid >> 2;           // 0..127
    const int sch  = (((tid & 3) ^ ((tid >> 3) & 3))) * 8;
    const bf16* pA0 = A + (size_t)(bm + srow) * KDIM + kBase + sch;
    const bf16* pA1 = pA0 + (size_t)128 * KDIM;
    const bf16* pB0 = B + (size_t)(bcol + srow) * KDIM + kBase + sch;
    const bf16* pB1 = pB0 + (size_t)128 * KDIM;

    bf16* ldswA = lds + wave * 512;            // wave segment, A region
    bf16* ldswB = lds + 32768 + wave * 512;    // wave segment, B region

#define STAGE_A(s, offB) do {                                                  \
    GLOAD_LDS16((const char*)pA0 + (offB), ldswA + (s) * 8192);                \
    GLOAD_LDS16((const char*)pA1 + (offB), ldswA + (s) * 8192 + 4096); } while (0)
#define STAGE_B(s, offB) do {                                                  \
    GLOAD_LDS16((const char*)pB0 + (offB), ldswB + (s) * 8192);                \
    GLOAD_LDS16((const char*)pB1 + (offB), ldswB + (s) * 8192 + 4096); } while (0)

    // prologue: halves 0,1,2 of each operand at byte offsets 0,64,128
    STAGE_A(0, 0);   STAGE_B(0, 0);
    STAGE_A(1, 64);  STAGE_B(1, 64);
    STAGE_A(2, 128); STAGE_B(2, 128);
    asm volatile("s_waitcnt vmcnt(4)" ::: "memory");   // A0,B0,A1,B1 landed
    __builtin_amdgcn_s_barrier();

    const int rowk = lane & 15;
    const int kc   = lane >> 4;
    const int kx2  = (kc ^ ((rowk >> 1) & 3)) * 16;    // swizzled 16B-chunk byte off

    const char* ldsB8 = (const char*)lds;
    int aoff[8], boff[4];
#pragma unroll
    for (int m = 0; m < 8; ++m) aoff[m] = (wr + m * 16 + rowk) * 64 + kx2;
#pragma unroll
    for (int n = 0; n < 4; ++n) boff[n] = 65536 + (wc + n * 16 + rowk) * 64 + kx2;

#define LDSA(s, m) (*(const bf16x8*)(ldsB8 + (s) * 16384 + aoff[m]))
#define LDSB(s, n) (*(const bf16x8*)(ldsB8 + ((s) - 4) * 16384 + boff[n]))

    bf16x8 a[4], b[4], a2[4], b2[4];
#pragma unroll
    for (int m = 0; m < 4; ++m) a[m] = LDSA(0, m);
#pragma unroll
    for (int n = 0; n < 4; ++n) b[n] = LDSB(4, n);

    // Per-tile phases (P = t&1 literal):
    //  P1: stage A(2t+3)[slot 3-2P]; read a2 = A(2P) Mhigh;    MFMA lo  (a ,b )
    //  P2: stage B(2t+3)[slot 7-2P]; read a  = A(2P+1) Mlow,
    //                                      b2 = B(5+2P);       MFMA hi  (a2,b )
    //  P3: stage A(2t+4)[slot 2P];   read a2 = A(2P+1) Mhigh;  MFMA lo  (a ,b2)
    //  P4: stage B(2t+4)[slot 4+2P]; MFMA hi (a2,b2); vmcnt(4);
    //      prefetch next tile a=A(2-2P) Mlow, b=B(6-2P); barrier; ptr+=128B
#define TILE(t_, P)                                                            \
  {                                                                            \
    /* ---- phase 1 ---- */                                                    \
    if ((t_) <= NT8 - 2) STAGE_A(3 - 2*(P), 192);                              \
    _Pragma("unroll") for (int m = 0; m < 4; ++m) a2[m] = LDSA(2*(P), 4 + m);  \
    __builtin_amdgcn_sched_barrier(0);                                         \
    __builtin_amdgcn_s_setprio(1);                                             \
    _Pragma("unroll") for (int m = 0; m < 4; ++m)                              \
    _Pragma("unroll") for (int n = 0; n < 4; ++n)                              \
      acc[m][n] = __builtin_amdgcn_mfma_f32_16x16x32_bf16(a[m], b[n], acc[m][n], 0, 0, 0); \
    __builtin_amdgcn_s_setprio(0);                                             \
    __builtin_amdgcn_s_barrier();                                              \
    /* ---- phase 2 ---- */                                                    \
    if ((t_) <= NT8 - 2) STAGE_B(3 - 2*(P), 192);                              \
    _Pragma("unroll") for (int m = 0; m < 4; ++m) a[m]  = LDSA(2*(P) + 1, m);  \
    _Pragma("unroll") for (int n = 0; n < 4; ++n) b2[n] = LDSB(5 + 2*(P), n);  \
    __builtin_amdgcn_sched_barrier(0);                                         \
    __builtin_amdgcn_s_setprio(1);                                             \
    _Pragma("unroll") for (int m = 0; m < 4; ++m)                              \
    _Pragma("unroll") for (int n = 0; n < 4; ++n)                              \
      acc[4 + m][n] = __builtin_amdgcn_mfma_f32_16x16x32_bf16(a2[m], b[n], acc[4 + m][n], 0, 0, 0); \
    __builtin_amdgcn_s_setprio(0);                                             \
    __builtin_amdgcn_s_barrier();                                              \
    /* ---- phase 3 ---- */                                                    \
    if ((t_) <= NT8 - 3) STAGE_A(2*(P), 256);                                  \
    _Pragma("unroll") for (int m = 0; m < 4; ++m) a2[m] = LDSA(2*(P) + 1, 4 + m); \
    __builtin_amdgcn_sched_barrier(0);                                         \
    __builtin_amdgcn_s_setprio(1);                                             \
    _Pragma("unroll") for (int m = 0; m < 4; ++m)                              \
    _Pragma("unroll") for (int n = 0; n < 4; ++n)                              \
      acc[m][n] = __builtin_amdgcn_mfma_f32_16x16x32_bf16(a[m], b2[n], acc[m][n], 0, 0, 0); \
    __builtin_amdgcn_s_setprio(0);                                             \
    __builtin_amdgcn_s_barrier();                                              \
    /* ---- phase 4 ---- */                                                    \
    if ((t_) <= NT8 - 3) STAGE_B(2*(P), 256);                                  \
    __builtin_amdgcn_sched_barrier(0);                                         \
    __builtin_amdgcn_s_setprio(1);                                             \
    _Pragma("unroll") for (int m = 0; m < 4; ++m)                              \
    _Pragma("unroll") for (int n = 0; n < 4; ++n)                              \
      acc[4 + m][n] = __builtin_amdgcn_mfma_f32_16x16x32_bf16(a2[m], b2[n], acc[4 + m][n], 0, 0, 0); \
    __builtin_amdgcn_s_setprio(0);                                             \
    if ((t_) < NT8 - 2)       asm volatile("s_waitcnt vmcnt(4)" ::: "memory"); \
    else if ((t_) == NT8 - 2) asm volatile("s_waitcnt vmcnt(0)" ::: "memory"); \
    if ((t_) + 1 < NT8) {                                                      \
      _Pragma("unroll") for (int m = 0; m < 4; ++m) a[m] = LDSA(2 - 2*(P), m); \
      _Pragma("unroll") for (int n = 0; n < 4; ++n) b[n] = LDSB(6 - 2*(P), n); \
    }                                                                          \
    __builtin_amdgcn_s_barrier();                                              \
    pA0 += 64; pA1 += 64; pB0 += 64; pB1 += 64;                                \
  }

    for (int tt = 0; tt < NT8; tt += 2) {
        TILE(tt, 0)
        TILE(tt + 1, 1)
    }
#undef TILE
#undef LDSA
#undef LDSB
#undef STAGE_A
#undef STAGE_B

    // epilogue: C/D layout col = lane&15, row = (lane>>4)*4 + r
    const int ccol = lane & 15;
    const int crow = (lane >> 4) * 4;
#pragma unroll
    for (int mf = 0; mf < 8; ++mf) {
#pragma unroll
        for (int nf = 0; nf < 4; ++nf) {
            float* cp = C + (size_t)(bm + wr + mf * 16 + crow) * OUT_F + (bcol + wc + nf * 16 + ccol);
#pragma unroll
            for (int r = 0; r < 4; ++r)
                cp[(size_t)r * OUT_F] = acc[mf][nf][r];
        }
    }
}

// -------------------------------------------------------------------------
// Kernel 3: sum SPLIT partial C buffers into out (float4-vectorized).
// -------------------------------------------------------------------------
__global__ __launch_bounds__(256) void reduce_partials(const float4* __restrict__ P,
                                                       float4* __restrict__ out,
                                                       int n4)
{
    const int stride = gridDim.x * 256;
    for (int i = blockIdx.x * 256 + threadIdx.x; i < n4; i += stride) {
        float4 s = P[i];
#pragma unroll
        for (int p = 1; p < SPLIT; ++p) {
            const float4 q = P[(size_t)p * n4 + i];
            s.x += q.x; s.y += q.y; s.z += q.z; s.w += q.w;
        }
        out[i] = s;
    }
}

// -------------------------------------------------------------------------
extern "C" void kernel_launch(void* const* d_in, const int* in_sizes, int n_in,
                              void* d_out, int out_size, void* d_ws, size_t ws_size,
                              hipStream_t stream)
{
    const float* x  = (const float*)d_in[0];   // (4096,1024)
    const float* bw = (const float*)d_in[1];   // (1024,1024)
    const float* sw = (const float*)d_in[2];   // (1024,1024,8)
    const float* sc = (const float*)d_in[3];   // (1024,1024)
    const float* gr = (const float*)d_in[4];   // (1024,12) all rows equal
    float* out = (float*)d_out;                // (4096,1024)

    bf16* A = (bf16*)d_ws;                          // 4096*9216*2 = 75.5 MB
    bf16* W = A + (size_t)BATCH * KDIM;             // 1024*9216*2 = 18.9 MB
    float* parts = (float*)(W + (size_t)OUT_F * KDIM);   // 4 x 16.8 MB

    prep<<<NB_BUILD + NB_PACK, 256, 0, stream>>>(x, gr, bw, sw, sc, A, W);

    const int nblk = (BATCH / BM8) * (OUT_F / BN8) * SPLIT;   // 256
    gemm8<<<nblk, 512, 0, stream>>>(A, W, parts);

    const int n4 = BATCH * OUT_F / 4;
    reduce_partials<<<2048, 256, 0, stream>>>((const float4*)parts, (float4*)out, n4);
}

// Round 15
// 121.185 us; speedup vs baseline: 1.1538x; 1.1538x over previous
//
#include <hip/hip_runtime.h>
#include <hip/hip_bf16.h>
#include <stdint.h>
#include <stddef.h>

// Problem constants (from reference)
#define IN_F     1024
#define OUT_F    1024
#define BATCH    4096
#define NSPLINE  8            // GRID_SIZE + SPLINE_ORDER
#define KDIM     (IN_F * 9)   // 9216 : plane 0 = silu(x), planes 1..8 = spline basis
#define GRIDPTS  12           // GRID_SIZE + 2*SPLINE_ORDER + 1

typedef __bf16 bf16;
typedef __bf16 bf16x2 __attribute__((ext_vector_type(2)));
typedef __bf16 bf16x8 __attribute__((ext_vector_type(8)));
typedef float  f32x4  __attribute__((ext_vector_type(4)));

// -------------------------------------------------------------------------
// Kernel 1 (fused prep), vectorized stores: each thread handles TWO adjacent
// i-elements and writes bf16x2 (4 B/lane, full-rate coalescing vs 2 B/lane
// scalar). Blocks [0,8192) build A; blocks [8192,10240) pack W.
// -------------------------------------------------------------------------
#define NB_BUILD (BATCH * IN_F / 512)   // 8192
#define NB_PACK  (OUT_F * IN_F / 512)   // 2048

__global__ __launch_bounds__(256) void prep(const float* __restrict__ x,
                                            const float* __restrict__ grid,
                                            const float* __restrict__ bw,
                                            const float* __restrict__ sw,
                                            const float* __restrict__ sc,
                                            bf16* __restrict__ A,
                                            bf16* __restrict__ W)
{
    __shared__ float g[GRIDPTS];
    __shared__ float rec[33];   // rec[(k-1)*11 + j] = 1/(g[j+k]-g[j]+1e-8)

    if (blockIdx.x < NB_BUILD) {
        // ---------------- build_A (2 elements/thread) ----------------
        if (threadIdx.x < GRIDPTS) g[threadIdx.x] = grid[threadIdx.x];  // row 0
        __syncthreads();
        if (threadIdx.x < 33) {
            const int k = threadIdx.x / 11 + 1;
            const int j = threadIdx.x % 11;
            if (j + k <= 11) rec[threadIdx.x] = 1.0f / (g[j + k] - g[j] + 1e-8f);
        }
        __syncthreads();

        const int idx2 = blockIdx.x * 256 + threadIdx.x;  // pair index
        const int e0 = idx2 * 2;                          // b*IN_F + i (i even)
        const int b = e0 >> 10;
        const int i = e0 & 1023;
        const float2 xv2 = *(const float2*)(x + e0);

        float bs[2][11];
#pragma unroll
        for (int u = 0; u < 2; ++u) {
            const float xv = u ? xv2.y : xv2.x;
#pragma unroll
            for (int j = 0; j < 11; ++j)
                bs[u][j] = (xv >= g[j] && xv < g[j + 1]) ? 1.0f : 0.0f;
#pragma unroll
            for (int k = 1; k <= 3; ++k) {
                const float* rk = &rec[(k - 1) * 11];
#pragma unroll
                for (int j = 0; j < 10; ++j) {
                    if (j <= 10 - k) {
                        bs[u][j] = (xv - g[j]) * rk[j] * bs[u][j]
                                 + (g[j + k + 1] - xv) * rk[j + 1] * bs[u][j + 1];
                    }
                }
            }
        }

        const float s0 = xv2.x / (1.0f + __expf(-xv2.x));
        const float s1 = xv2.y / (1.0f + __expf(-xv2.y));

        bf16* rowp = A + (size_t)b * KDIM;
        *(bf16x2*)&rowp[i] = (bf16x2){(bf16)s0, (bf16)s1};
#pragma unroll
        for (int j = 0; j < NSPLINE; ++j)
            *(bf16x2*)&rowp[(size_t)(j + 1) * IN_F + i] =
                (bf16x2){(bf16)bs[0][j], (bf16)bs[1][j]};
    } else {
        // ---------------- pack_W (2 elements/thread) ----------------
        const int idx2 = (blockIdx.x - NB_BUILD) * 256 + threadIdx.x;
        const int e0 = idx2 * 2;                          // o*IN_F + i (i even)
        const int i = e0 & 1023;
        const float2 s2 = *(const float2*)(sc + e0);
        const float2 bw2 = *(const float2*)(bw + e0);

        bf16* rowp = W + (size_t)(e0 >> 10) * KDIM;
        *(bf16x2*)&rowp[i] = (bf16x2){(bf16)bw2.x, (bf16)bw2.y};

        const float4* swv = (const float4*)(sw + (size_t)e0 * NSPLINE);
        const float4 a0 = swv[0], a1 = swv[1];   // element e0
        const float4 c0 = swv[2], c1 = swv[3];   // element e0+1
        float w0[NSPLINE] = {a0.x, a0.y, a0.z, a0.w, a1.x, a1.y, a1.z, a1.w};
        float w1[NSPLINE] = {c0.x, c0.y, c0.z, c0.w, c1.x, c1.y, c1.z, c1.w};
#pragma unroll
        for (int j = 0; j < NSPLINE; ++j)
            *(bf16x2*)&rowp[(size_t)(j + 1) * IN_F + i] =
                (bf16x2){(bf16)(w0[j] * s2.x), (bf16)(w1[j] * s2.y)};
    }
}

// -------------------------------------------------------------------------
// Kernel 2: 256x256x64 pipelined 4-phase split-K GEMM (T1+T2+T4+T5).
// r12 verbatim — twice-verified optimum: 78.5-79.2 us, 0 bank conflicts,
// MfmaUtil 40%, VGPR 104. Ring of 8 LDS half-slots, counted vmcnt,
// cross-phase ds_read pipelining, T2 chunk-XOR swizzle w/ pre-permuted src.
// -------------------------------------------------------------------------
#define BM8 256
#define BN8 256
#define BK8 64
#define SPLIT 4

#define GLOAD_LDS16(gp, lp)                                                          \
    __builtin_amdgcn_global_load_lds((const __attribute__((address_space(1))) void*)(gp), \
                                     (__attribute__((address_space(3))) void*)(lp), 16, 0, 0)

__global__ __launch_bounds__(512, 2) void gemm8(const bf16* __restrict__ A,
                                                const bf16* __restrict__ B,
                                                float* __restrict__ C,
                                                int kLen)
{
    __shared__ bf16 lds[8 * 8192];   // 8 half-slots x 16 KB = 128 KB

    const int tid  = threadIdx.x;
    const int wave = tid >> 6;
    const int lane = tid & 63;

    // bijective XCD swizzle (gridDim.x % 8 == 0)
    const int nwg  = gridDim.x;
    const int q    = nwg >> 3;
    const int wgid = (blockIdx.x & 7) * q + (blockIdx.x >> 3);
    const int nxy  = (BATCH / BM8) * (OUT_F / BN8);   // 16*4 = 64
    const int z    = wgid / nxy;
    const int rem  = wgid - z * nxy;
    const int by   = rem >> 4;           // 0..3
    const int bx   = rem & 15;           // 0..15

    const int bm   = bx * BM8;
    const int bcol = by * BN8;
    const int kBase = z * kLen;
    C += (size_t)z * BATCH * OUT_F;      // partial buffer for this K-slice

    const int wr = (wave >> 2) * 128;    // 2 M-waves
    const int wc = (wave & 3) * 64;      // 4 N-waves

    f32x4 acc[8][4] = {};

    const int NT   = kLen / BK8;
    const int hmax = 4 * NT;

    // staging geometry: thread covers row tid/4; global k-chunk pre-swizzled
    // so the linear LDS write lands data where the swizzled reader expects.
    const int srow = tid >> 2;           // 0..127
    const int sch  = (((tid & 3) ^ ((tid >> 3) & 3))) * 8;
    const bf16* baseA = A + (size_t)(bm + srow) * KDIM + kBase + sch;
    const bf16* baseB = B + (size_t)(bcol + srow) * KDIM + kBase + sch;
    const size_t rstep = (size_t)128 * KDIM;
    bf16* ldsw = &lds[wave * 512];       // wave-uniform dest segment

    auto stage = [&](int h) {
        if (h < hmax) {
            const int t   = h >> 2;
            const int th  = h & 3;
            const int kof = t * BK8 + ((th >> 1) ? 32 : 0);
            const bf16* src = (th & 1) ? baseB : baseA;
            bf16* l0 = ldsw + (h & 7) * 8192;
            GLOAD_LDS16(src + kof, l0);
            GLOAD_LDS16(src + kof + rstep, l0 + 4096);
        }
    };

    // prologue: stage halves 0..5; vmcnt(4) -> halves 0..3 landed; barrier
    for (int h = 0; h < 6; ++h) stage(h);
    asm volatile("s_waitcnt vmcnt(4)" ::: "memory");
    __builtin_amdgcn_s_barrier();

    const int rowk = lane & 15;
    const int kc   = lane >> 4;          // logical 8-elem k-chunk 0..3
    // (row>>1)&3 == (rowk>>1)&3 for all rows we touch (wr,wc,m*16 ≡ 0 mod 8)
    const int kxor = (kc ^ ((rowk >> 1) & 3)) * 8;

#define LDSFRAG(slot, row) (*(const bf16x8*)&lds[(slot) * 8192 + (row) * 32 + kxor])

    bf16x8 a[4], b[4], a2[4], b2[4];
    // initial reads: tile 0 phase 1 operands (slots 0 = A-kh0, 1 = B-kh0)
#pragma unroll
    for (int m = 0; m < 4; ++m) a[m] = LDSFRAG(0, wr + m * 16 + rowk);
#pragma unroll
    for (int n = 0; n < 4; ++n) b[n] = LDSFRAG(1, wc + n * 16 + rowk);

    for (int t = 0; t < NT; ++t) {
        const int h0  = 4 * t;
        const int sA0 = (h0 + 0) & 7;
        const int sA1 = (h0 + 2) & 7, sB1 = (h0 + 3) & 7;

        // ---- phase 1: acc_lo += a(kh0,Mlow) x b(kh0); prefetch a2 = kh0,Mhigh
        stage(h0 + 6);
#pragma unroll
        for (int m = 0; m < 4; ++m) a2[m] = LDSFRAG(sA0, wr + 64 + m * 16 + rowk);
        __builtin_amdgcn_sched_barrier(0);
        __builtin_amdgcn_s_setprio(1);
#pragma unroll
        for (int m = 0; m < 4; ++m)
#pragma unroll
            for (int n = 0; n < 4; ++n)
                acc[m][n] = __builtin_amdgcn_mfma_f32_16x16x32_bf16(a[m], b[n], acc[m][n], 0, 0, 0);
        __builtin_amdgcn_s_setprio(0);
        __builtin_amdgcn_s_barrier();

        // ---- phase 2: acc_hi += a2 x b; prefetch a = kh1,Mlow and b2 = kh1
        stage(h0 + 7);
#pragma unroll
        for (int m = 0; m < 4; ++m) a[m] = LDSFRAG(sA1, wr + m * 16 + rowk);
#pragma unroll
        for (int n = 0; n < 4; ++n) b2[n] = LDSFRAG(sB1, wc + n * 16 + rowk);
        __builtin_amdgcn_sched_barrier(0);
        __builtin_amdgcn_s_setprio(1);
#pragma unroll
        for (int m = 0; m < 4; ++m)
#pragma unroll
            for (int n = 0; n < 4; ++n)
                acc[4 + m][n] = __builtin_amdgcn_mfma_f32_16x16x32_bf16(a2[m], b[n], acc[4 + m][n], 0, 0, 0);
        __builtin_amdgcn_s_setprio(0);
        __builtin_amdgcn_s_barrier();

        // ---- phase 3: acc_lo += a x b2; prefetch a2 = kh1,Mhigh
        stage(h0 + 8);
#pragma unroll
        for (int m = 0; m < 4; ++m) a2[m] = LDSFRAG(sA1, wr + 64 + m * 16 + rowk);
        __builtin_amdgcn_sched_barrier(0);
        __builtin_amdgcn_s_setprio(1);
#pragma unroll
        for (int m = 0; m < 4; ++m)
#pragma unroll
            for (int n = 0; n < 4; ++n)
                acc[m][n] = __builtin_amdgcn_mfma_f32_16x16x32_bf16(a[m], b2[n], acc[m][n], 0, 0, 0);
        __builtin_amdgcn_s_setprio(0);
        __builtin_amdgcn_s_barrier();

        // ---- phase 4: acc_hi += a2 x b2; vmcnt; prefetch next tile's a,b
        stage(h0 + 9);
        __builtin_amdgcn_sched_barrier(0);
        __builtin_amdgcn_s_setprio(1);
#pragma unroll
        for (int m = 0; m < 4; ++m)
#pragma unroll
            for (int n = 0; n < 4; ++n)
                acc[4 + m][n] = __builtin_amdgcn_mfma_f32_16x16x32_bf16(a2[m], b2[n], acc[4 + m][n], 0, 0, 0);
        __builtin_amdgcn_s_setprio(0);
        // counted per-tile wait: halves <= 4t+7 landed; never drain mid-loop
        if (t < NT - 2)       asm volatile("s_waitcnt vmcnt(4)" ::: "memory");
        else if (t == NT - 2) asm volatile("s_waitcnt vmcnt(0)" ::: "memory");
        if (t + 1 < NT) {
            const int nA0 = (h0 + 4) & 7, nB0 = (h0 + 5) & 7;
#pragma unroll
            for (int m = 0; m < 4; ++m) a[m] = LDSFRAG(nA0, wr + m * 16 + rowk);
#pragma unroll
            for (int n = 0; n < 4; ++n) b[n] = LDSFRAG(nB0, wc + n * 16 + rowk);
        }
        __builtin_amdgcn_s_barrier();
    }
#undef LDSFRAG

    // epilogue: C/D layout col = lane&15, row = (lane>>4)*4 + r
    const int ccol = lane & 15;
    const int crow = (lane >> 4) * 4;
#pragma unroll
    for (int mf = 0; mf < 8; ++mf) {
#pragma unroll
        for (int nf = 0; nf < 4; ++nf) {
            float* cp = C + (size_t)(bm + wr + mf * 16 + crow) * OUT_F + (bcol + wc + nf * 16 + ccol);
#pragma unroll
            for (int r = 0; r < 4; ++r)
                cp[(size_t)r * OUT_F] = acc[mf][nf][r];
        }
    }
}

// -------------------------------------------------------------------------
// Kernel 3: sum SPLIT partial C buffers into out (float4-vectorized).
// -------------------------------------------------------------------------
__global__ __launch_bounds__(256) void reduce_partials(const float4* __restrict__ P,
                                                       float4* __restrict__ out,
                                                       int n4)
{
    const int stride = gridDim.x * 256;
    for (int i = blockIdx.x * 256 + threadIdx.x; i < n4; i += stride) {
        float4 s = P[i];
#pragma unroll
        for (int p = 1; p < SPLIT; ++p) {
            const float4 q = P[(size_t)p * n4 + i];
            s.x += q.x; s.y += q.y; s.z += q.z; s.w += q.w;
        }
        out[i] = s;
    }
}

// -------------------------------------------------------------------------
extern "C" void kernel_launch(void* const* d_in, const int* in_sizes, int n_in,
                              void* d_out, int out_size, void* d_ws, size_t ws_size,
                              hipStream_t stream)
{
    const float* x  = (const float*)d_in[0];   // (4096,1024)
    const float* bw = (const float*)d_in[1];   // (1024,1024)
    const float* sw = (const float*)d_in[2];   // (1024,1024,8)
    const float* sc = (const float*)d_in[3];   // (1024,1024)
    const float* gr = (const float*)d_in[4];   // (1024,12) all rows equal
    float* out = (float*)d_out;                // (4096,1024)

    bf16* A = (bf16*)d_ws;                          // 4096*9216*2 = 75.5 MB
    bf16* W = A + (size_t)BATCH * KDIM;             // 1024*9216*2 = 18.9 MB
    float* parts = (float*)(W + (size_t)OUT_F * KDIM);   // 4 x 16.8 MB

    prep<<<NB_BUILD + NB_PACK, 256, 0, stream>>>(x, gr, bw, sw, sc, A, W);

    const int nblk = (BATCH / BM8) * (OUT_F / BN8) * SPLIT;   // 256
    gemm8<<<nblk, 512, 0, stream>>>(A, W, parts, KDIM / SPLIT);

    const int n4 = BATCH * OUT_F / 4;
    reduce_partials<<<2048, 256, 0, stream>>>((const float4*)parts, (float4*)out, n4);
}